// Round 6
// baseline (263.869 us; speedup 1.0000x reference)
//
#include <hip/hip_runtime.h>
#include <hip/hip_bf16.h>

// ---------------- problem constants ----------------
constexpr long NN = 20000;   // nodes
constexpr long NE = 160000;  // edges
constexpr long BB = 200;     // graphs
constexpr long TT = 8;       // taus
constexpr long GN = 100;     // nodes per graph

// ---------------- ws layout (f32 element offsets) ----------------
constexpr long O_FLAG = 0;                                      // int mode flag
constexpr long O_X    = 16;                 constexpr long N_X   = 40000;
constexpr long O_TAU  = O_X + N_X;          constexpr long N_TAU = 1600;
constexpr long O_W1   = O_TAU + N_TAU;      constexpr long N_W1  = 4096;
constexpr long O_Q1   = O_W1 + N_W1;        constexpr long N_Q   = 2048;
constexpr long O_K1   = O_Q1 + N_Q;
constexpr long O_B1   = O_K1 + N_Q;         constexpr long N_B   = 128;
constexpr long O_W2   = O_B1 + N_B;         constexpr long N_W2  = 262144;
constexpr long O_Q2   = O_W2 + N_W2;
constexpr long O_K2   = O_Q2 + N_Q;
constexpr long O_B2   = O_K2 + N_Q;
constexpr long O_CW   = O_B2 + N_B;         constexpr long N_CW  = 8192;
constexpr long O_CB   = O_CW + N_CW;
constexpr long O_F1W  = O_CB + N_B;         constexpr long N_FW  = 16384;
constexpr long O_F1B  = O_F1W + N_FW;
constexpr long O_F1SW = O_F1B + N_B;
constexpr long O_F1SB = O_F1SW + N_FW;
constexpr long O_F1EW = O_F1SB + N_B;
constexpr long O_F1EB = O_F1EW + N_FW;
constexpr long O_F2W  = O_F1EB + N_B;
constexpr long O_F2B  = O_F2W + N_FW;
constexpr long O_F2SW = O_F2B + N_B;
constexpr long O_F2SB = O_F2SW + N_FW;
constexpr long O_F2EW = O_F2SB + N_B;
constexpr long O_F2EB = O_F2EW + N_FW;
constexpr long O_AW   = O_F2EB + N_B;       constexpr long N_AW  = 1280;
constexpr long O_AB   = O_AW + N_AW;        constexpr long N_AB  = 16;  // 10 used
constexpr long O_ASW  = O_AB + N_AB;
constexpr long O_ASB  = O_ASW + N_AW;
constexpr long O_AEW  = O_ASB + N_AB;
constexpr long O_AEB  = O_AEW + N_AW;
constexpr long O_VW   = O_AEB + N_AB;       constexpr long N_VW  = 128;
constexpr long O_VB   = O_VW + N_VW;        constexpr long N_VB  = 16;  // 1 used
constexpr long O_VSW  = O_VB + N_VB;
constexpr long O_VSB  = O_VSW + N_VW;
constexpr long O_VEW  = O_VSB + N_VB;
constexpr long O_VEB  = O_VEW + N_VW;
// derived
constexpr long O_WQ1  = O_VEB + N_VB;       // [4][2][4] = 32  (r*8 + i*4 + h)
constexpr long O_WK1  = O_WQ1 + 32;
constexpr long O_WQ2  = O_WK1 + 32;         // [4][128][4] = 2048
constexpr long O_WK2  = O_WQ2 + 2048;
constexpr long O_CF1W = O_WK2 + 2048;       // combined noisy weights
constexpr long O_CF1B = O_CF1W + N_FW;
constexpr long O_CF2W = O_CF1B + N_B;
constexpr long O_CF2B = O_CF2W + N_FW;
constexpr long O_CAW  = O_CF2B + N_B;
constexpr long O_CAB  = O_CAW + N_AW;
constexpr long O_CVW  = O_CAB + N_AB;
constexpr long O_CVB  = O_CVW + N_VW;
constexpr long O_AL1  = O_CVB + N_VB;       // (spacer)
constexpr long O_AL2  = O_AL1 + NE*4;
constexpr long O_H1   = O_AL2 + NE*4;       // (spacer, f32 H1 removed)
constexpr long O_H2   = O_H1 + NN*128;
constexpr long O_G    = O_H2 + NN*128;
constexpr long O_Z0   = O_G + BB*128;
constexpr long O_Z1   = O_Z0 + BB*TT*128;
constexpr long O_Z2   = O_Z1 + BB*TT*128;
// CSR region
constexpr long O_AGG1 = O_Z2 + BB*TT*128;
constexpr long O_DEG  = O_AGG1;             // [NN] int
constexpr long O_CUR  = O_DEG + NN;         // [NN] int
constexpr long O_ROWP = O_CUR + NN;         // [NN+1] int (+pad)
constexpr long O_PERM = O_ROWP + NN + 8;    // [NE] int
constexpr long O_AGG2 = O_AGG1 + NN*128;
constexpr long O_DEN1 = O_AGG2 + NN*128;
constexpr long O_DEN2 = O_DEN1 + NN*4;
constexpr long O_AMAX1= O_DEN2 + NN*4;
constexpr long O_AMAX2= O_AMAX1 + NN*4;
// bf16 xw2 table [N][4][512] — inner 512 ordered d*4+h (viewed as u16)
constexpr long O_XW2  = O_AMAX2 + NN*4;
constexpr long O_END_TABLE = O_XW2 + (NN*4*512)/2;
// MFMA-path extras
constexpr long MPAD   = 20096;
constexpr long O_H1B  = O_END_TABLE;                  // [20096][128] bf16
constexpr long O_W2BT = O_H1B + (MPAD*128)/2;         // [2048][128] bf16, row-permuted
constexpr long O_END2 = O_W2BT + (2048L*128)/2;
// AQ/AK tables: [N][16] f32, idx = r*4+h
constexpr long O_AQ   = O_END2;
constexpr long O_AK   = O_AQ + NN*16;
constexpr long O_END3 = O_AK + NN*16;

constexpr int EMAX = 128;

#define DEVFN __device__ __forceinline__

typedef __attribute__((ext_vector_type(8))) short bf16x8;
typedef __attribute__((ext_vector_type(4))) float f32x4;
typedef __attribute__((ext_vector_type(4))) unsigned short u16x4;

DEVFN float selu_f(float x){ return 1.0507009873554805f * (x > 0.f ? x : 1.6732632423543772f * expm1f(x)); }
DEVFN float lrelu_f(float x){ return x >= 0.f ? x : 0.2f * x; }
DEVFN float bf2f(unsigned short u){ return __uint_as_float(((unsigned)u) << 16); }

// ---------------- fused detect + histogram ----------------
__global__ void k_pre(const unsigned short* taus_u16, const int* ei, float* ws){
    if (blockIdx.x == 0){
        if (threadIdx.x == 0){
            int bf = 1;
            for (int i = 0; i < 128; i++) if (taus_u16[i] > 0x3F80u){ bf = 0; break; }
            ((int*)ws)[0] = bf;
        }
        return;
    }
    long e = (long)(blockIdx.x - 1)*blockDim.x + threadIdx.x;
    if (e >= NE) return;
    atomicAdd((int*)(ws + O_DEG) + ei[NE + e], 1);
}

__global__ void k_scan(float* ws){
    const int* deg = (const int*)(ws + O_DEG);
    int* rowp = (int*)(ws + O_ROWP);
    __shared__ int part[256];
    int tid = threadIdx.x;
    int base = tid * 79;
    int n = 0; if (base < NN) n = min(79, (int)NN - base);
    int s = 0;
    for (int i = 0; i < n; i++) s += deg[base + i];
    part[tid] = s;
    __syncthreads();
    if (tid == 0){
        int acc = 0;
        for (int i = 0; i < 256; i++){ int t = part[i]; part[i] = acc; acc += t; }
    }
    __syncthreads();
    int acc = part[tid];
    for (int i = 0; i < n; i++){ rowp[base + i] = acc; acc += deg[base + i]; }
    if (tid == 0) rowp[NN] = (int)NE;
}

// ---------------- fused convert (y<38) + CSR scatter (y=38) ----------------
struct ConvArgs { const void* src[38]; long off[38]; int n[38]; };

__global__ void k_conv_scatter(ConvArgs a, const int* ei, float* ws){
    int y = blockIdx.y;
    if (y == 38){
        long e = (long)blockIdx.x*blockDim.x + threadIdx.x;
        if (e >= NE) return;
        int dst = ei[NE + e];
        int pos = atomicAdd((int*)(ws + O_CUR) + dst, 1);
        ((int*)(ws + O_PERM))[((const int*)(ws + O_ROWP))[dst] + pos] = (int)e;
        return;
    }
    long off = a.off[y];
    if (off < 0) return;
    const void* s = a.src[y];
    int n = a.n[y];
    int bf = ((const int*)ws)[0];
    for (int i = blockIdx.x*blockDim.x + threadIdx.x; i < n; i += gridDim.x*blockDim.x){
        float v;
        if (bf){ unsigned short u = ((const unsigned short*)s)[i]; v = bf2f(u); }
        else   { v = ((const float*)s)[i]; }
        ws[off + i] = v;
    }
}

// ---------------- fused prep: fold + noisy + w2b + zpad ----------------
__global__ void k_prep(float* ws){
    int phase = blockIdx.y;
    int idx = blockIdx.x*blockDim.x + threadIdx.x;
    if (phase == 0){
        if (idx >= 4160) return;
        long wsrc, qsrc, dst; int ri, h;
        if (idx < 64){
            int t = idx & 31; h = t & 3; ri = t >> 2;
            wsrc = O_W1 + (long)ri*512;
            qsrc = (idx < 32) ? O_Q1 : O_K1;
            dst  = ((idx < 32) ? O_WQ1 : O_WK1) + t;
        } else {
            int t = (idx - 64) & 2047; h = t & 3; ri = t >> 2;
            wsrc = O_W2 + (long)ri*512;
            qsrc = (idx < 2112) ? O_Q2 : O_K2;
            dst  = ((idx < 2112) ? O_WQ2 : O_WK2) + t;
        }
        const float* W = ws + wsrc;
        const float* Q = ws + qsrc;
        float s = 0.f;
        for (int o = 0; o < 512; o++) s += W[o] * Q[o*4 + h];
        ws[dst] = s;
    } else if (phase == 1){
        const long tw[8] = {O_F1W,O_F2W,O_AW,O_VW, O_F1B,O_F2B,O_AB,O_VB};
        const long ts[8] = {O_F1SW,O_F2SW,O_ASW,O_VSW, O_F1SB,O_F2SB,O_ASB,O_VSB};
        const long te[8] = {O_F1EW,O_F2EW,O_AEW,O_VEW, O_F1EB,O_F2EB,O_AEB,O_VEB};
        const long td[8] = {O_CF1W,O_CF2W,O_CAW,O_CVW, O_CF1B,O_CF2B,O_CAB,O_CVB};
        const int  tn[8] = {16384,16384,1280,128, 128,128,10,1};
        const int  tb[8] = {0,16384,32768,34048, 34176,34304,34432,34442};
        int total = 34443;
        for (int i = idx; i < total; i += gridDim.x*blockDim.x){
            int t = 0;
            #pragma unroll
            for (int q = 1; q < 8; q++) if (i >= tb[q]) t = q;
            int j = i - tb[t];
            if (j < tn[t]) ws[td[t] + j] = ws[tw[t] + j] + ws[ts[t] + j]*ws[te[t] + j];
        }
    } else if (phase == 2){
        // W2 -> Bt row-permuted bf16: row n' = r*512 + d*4 + h holds W2[r][:,h*128+d]
        if (idx >= 262144) return;
        int np = idx & 2047, k = idx >> 11;
        int r = np >> 9, q = np & 511, d = q >> 2, h = q & 3;
        float v = ws[O_W2 + (long)r*65536 + (long)k*512 + h*128 + d];
        ((__hip_bfloat16*)(ws + O_W2BT))[(long)np*128 + k] = __float2bfloat16(v);
    } else {
        if (idx < 6144) ws[O_H1B + (20000L*128)/2 + idx] = 0.f;
    }
}

// ---------------- fused layer-1 node kernel (bf16 h1 output only) ----------------
__global__ void k_node1(const int* ei, const int* et, float* ws){
    __shared__ float wqk[64];
    __shared__ float alc[EMAX][4];
    __shared__ float xsc[EMAX][2];
    __shared__ int   rtc[EMAX];
    __shared__ float sacc[4][4][2];
    __shared__ float den[4], amax[4];
    __shared__ float mred[2][4];
    int n = blockIdx.x, tid = threadIdx.x;
    const int* rowp = (const int*)(ws + O_ROWP);
    const int* perm = (const int*)(ws + O_PERM);
    int e0 = rowp[n], deg = rowp[n+1] - e0;
    if (tid < 64) wqk[tid] = ws[O_WQ1 + tid];
    if (tid < 32) ((float*)sacc)[tid] = 0.f;
    if (tid < 4) den[tid] = 0.f;
    float xd0 = ws[O_X + (long)n*2], xd1 = ws[O_X + (long)n*2 + 1];
    __syncthreads();
    float mx[4] = {-3.0e38f,-3.0e38f,-3.0e38f,-3.0e38f};
    for (int j0 = 0; j0 < deg; j0 += 128){
        int j = j0 + tid;
        if (j < deg){
            int e = perm[e0 + j];
            int src = ei[e], rt = et[e];
            float xs0 = ws[O_X + (long)src*2], xs1 = ws[O_X + (long)src*2 + 1];
            const float* Wq = wqk + rt*8;
            const float* Wk = wqk + 32 + rt*8;
            #pragma unroll
            for (int h = 0; h < 4; h++){
                float a = lrelu_f(xd0*Wq[h] + xd1*Wq[4+h] + xs0*Wk[h] + xs1*Wk[4+h]);
                if (j < EMAX) alc[j][h] = a;
                mx[h] = fmaxf(mx[h], a);
            }
            if (j < EMAX){ xsc[j][0] = xs0; xsc[j][1] = xs1; rtc[j] = rt; }
        }
    }
    #pragma unroll
    for (int off = 32; off > 0; off >>= 1)
        #pragma unroll
        for (int h = 0; h < 4; h++) mx[h] = fmaxf(mx[h], __shfl_xor(mx[h], off));
    if ((tid & 63) == 0)
        #pragma unroll
        for (int h = 0; h < 4; h++) mred[tid >> 6][h] = mx[h];
    __syncthreads();
    if (tid < 4) amax[tid] = fmaxf(mred[0][tid], mred[1][tid]);
    __syncthreads();
    for (int j0 = 0; j0 < deg; j0 += 128){
        int j = j0 + tid;
        if (j < deg){
            float al[4], xs0, xs1; int rt;
            if (j < EMAX){
                #pragma unroll
                for (int h = 0; h < 4; h++) al[h] = alc[j][h];
                xs0 = xsc[j][0]; xs1 = xsc[j][1]; rt = rtc[j];
            } else {
                int e = perm[e0 + j];
                int src = ei[e]; rt = et[e];
                xs0 = ws[O_X + (long)src*2]; xs1 = ws[O_X + (long)src*2 + 1];
                const float* Wq = wqk + rt*8;
                const float* Wk = wqk + 32 + rt*8;
                #pragma unroll
                for (int h = 0; h < 4; h++)
                    al[h] = lrelu_f(xd0*Wq[h] + xd1*Wq[4+h] + xs0*Wk[h] + xs1*Wk[4+h]);
            }
            #pragma unroll
            for (int h = 0; h < 4; h++){
                float ex = expf(al[h] - amax[h]);
                atomicAdd(&den[h], ex);
                atomicAdd(&sacc[rt][h][0], ex*xs0);
                atomicAdd(&sacc[rt][h][1], ex*xs1);
            }
        }
    }
    __syncthreads();
    int d = tid;
    float rden[4];
    #pragma unroll
    for (int h = 0; h < 4; h++) rden[h] = den[h] > 0.f ? 0.25f/den[h] : 0.f;
    float v = 0.f;
    #pragma unroll
    for (int r = 0; r < 4; r++)
        #pragma unroll
        for (int h = 0; h < 4; h++){
            float w0 = ws[O_W1 + r*1024 +        h*128 + d];
            float w1 = ws[O_W1 + r*1024 + 512  + h*128 + d];
            v += rden[h]*(w0*sacc[r][h][0] + w1*sacc[r][h][1]);
        }
    float out = selu_f(v + ws[O_B1 + d]);
    ((__hip_bfloat16*)(ws + O_H1B))[(long)n*128 + d] = __float2bfloat16(out);
}

// ---------------- AQ/AK tables (from bf16 h1) ----------------
__global__ void k_aqk(float* ws){
    __shared__ float wq[128*16];
    __shared__ float wk[128*16];
    __shared__ float hl[16][129];
    int tid = threadIdx.x;
    long nb = (long)blockIdx.x * 16;
    const unsigned short* h1b = (const unsigned short*)(ws + O_H1B);
    #pragma unroll
    for (int c = 0; c < 8; c++){
        int idx = tid + c*256;
        int i = idx >> 4, o = idx & 15;
        int r = o >> 2, h = o & 3;
        wq[i*16 + o] = ws[O_WQ2 + r*512 + i*4 + h];
        wk[i*16 + o] = ws[O_WK2 + r*512 + i*4 + h];
        hl[idx >> 7][idx & 127] = bf2f(h1b[nb*128 + idx]);
    }
    __syncthreads();
    int j = tid >> 4, o = tid & 15;
    float aq = 0.f, ak = 0.f;
    #pragma unroll 4
    for (int i = 0; i < 128; i++){
        float hv = hl[j][i];
        aq += hv * wq[i*16 + o];
        ak += hv * wk[i*16 + o];
    }
    ws[O_AQ + (nb + j)*16 + o] = aq;
    ws[O_AK + (nb + j)*16 + o] = ak;
}

// ---------------- xw2 = h1 @ W2 via MFMA (B rows pre-permuted) ----------------
__global__ void k_xw2_mfma(float* ws){
    __shared__ __align__(16) unsigned short Ash[128*128];
    __shared__ __align__(16) unsigned short Bsh[128*128];
    const unsigned short* h1b  = (const unsigned short*)(ws + O_H1B);
    const unsigned short* w2bt = (const unsigned short*)(ws + O_W2BT);
    long bm = (long)blockIdx.x * 128;
    long bn = (long)blockIdx.y * 128;
    int tid = threadIdx.x;
    char* Ac = (char*)Ash; char* Bc = (char*)Bsh;
    #pragma unroll
    for (int i = 0; i < 8; i++){
        int c = tid + i*256;
        int row = c >> 4, kb = (c & 15) * 16;
        int off = row*256 + (kb ^ ((row & 7) << 4));
        *(bf16x8*)(Ac + off) = *(const bf16x8*)&h1b [(bm + row)*128 + (c & 15)*8];
        *(bf16x8*)(Bc + off) = *(const bf16x8*)&w2bt[(bn + row)*128 + (c & 15)*8];
    }
    __syncthreads();
    int w = tid >> 6, lane = tid & 63;
    int wm = (w >> 1) * 64, wn = (w & 1) * 64;
    int r16 = lane & 15, kq = lane >> 4;
    f32x4 acc[4][4] = {};
    #pragma unroll
    for (int ks = 0; ks < 4; ks++){
        int kbyte = ks*64 + kq*16;
        bf16x8 a[4], b[4];
        #pragma unroll
        for (int m = 0; m < 4; m++){
            int row = wm + m*16 + r16;
            a[m] = *(const bf16x8*)(Ac + row*256 + (kbyte ^ ((row & 7) << 4)));
        }
        #pragma unroll
        for (int n = 0; n < 4; n++){
            int row = wn + n*16 + r16;
            b[n] = *(const bf16x8*)(Bc + row*256 + (kbyte ^ ((row & 7) << 4)));
        }
        #pragma unroll
        for (int m = 0; m < 4; m++)
            #pragma unroll
            for (int n = 0; n < 4; n++)
                acc[m][n] = __builtin_amdgcn_mfma_f32_16x16x32_bf16(a[m], b[n], acc[m][n], 0, 0, 0);
    }
    __hip_bfloat16* xb = (__hip_bfloat16*)(ws + O_XW2);
    #pragma unroll
    for (int m = 0; m < 4; m++){
        long gr0 = bm + wm + m*16 + kq*4;
        #pragma unroll
        for (int j = 0; j < 4; j++){
            long gr = gr0 + j;
            if (gr < NN){
                #pragma unroll
                for (int n = 0; n < 4; n++){
                    long gc = bn + wn + n*16 + r16;
                    xb[gr*2048 + gc] = __float2bfloat16(acc[m][n][j]);
                }
            }
        }
    }
}

// ---------------- fused layer-2 node kernel (4-way unrolled gather) ----------------
__global__ void k_node2(const int* ei, const int* et, float* ws){
    __shared__ float aq[16];
    __shared__ float exc[EMAX][4];
    __shared__ int   esrt[EMAX];
    __shared__ float den[4], amax[4];
    __shared__ float mred[2][4];
    int n = blockIdx.x, tid = threadIdx.x;
    const int* rowp = (const int*)(ws + O_ROWP);
    const int* perm = (const int*)(ws + O_PERM);
    int e0 = rowp[n], deg = rowp[n+1] - e0;
    if (tid < 16) aq[tid] = ws[O_AQ + (long)n*16 + tid];
    if (tid < 4) den[tid] = 0.f;
    __syncthreads();
    float mx[4] = {-3.0e38f,-3.0e38f,-3.0e38f,-3.0e38f};
    for (int j0 = 0; j0 < deg; j0 += 128){
        int j = j0 + tid;
        if (j < deg){
            int e = perm[e0 + j];
            int src = ei[e], rt = et[e];
            float4 k4 = *(const float4*)&ws[O_AK + (long)src*16 + rt*4];
            float al0 = lrelu_f(aq[rt*4+0] + k4.x);
            float al1 = lrelu_f(aq[rt*4+1] + k4.y);
            float al2 = lrelu_f(aq[rt*4+2] + k4.z);
            float al3 = lrelu_f(aq[rt*4+3] + k4.w);
            if (j < EMAX){
                exc[j][0]=al0; exc[j][1]=al1; exc[j][2]=al2; exc[j][3]=al3;
                esrt[j] = src*4 + rt;
            }
            mx[0]=fmaxf(mx[0],al0); mx[1]=fmaxf(mx[1],al1);
            mx[2]=fmaxf(mx[2],al2); mx[3]=fmaxf(mx[3],al3);
        }
    }
    #pragma unroll
    for (int off = 32; off > 0; off >>= 1)
        #pragma unroll
        for (int h = 0; h < 4; h++) mx[h] = fmaxf(mx[h], __shfl_xor(mx[h], off));
    if ((tid & 63) == 0)
        #pragma unroll
        for (int h = 0; h < 4; h++) mred[tid >> 6][h] = mx[h];
    __syncthreads();
    if (tid < 4) amax[tid] = fmaxf(mred[0][tid], mred[1][tid]);
    __syncthreads();
    for (int j0 = 0; j0 < deg; j0 += 128){
        int j = j0 + tid;
        if (j < deg && j < EMAX){
            #pragma unroll
            for (int h = 0; h < 4; h++){
                float ex = expf(exc[j][h] - amax[h]);
                exc[j][h] = ex;
                atomicAdd(&den[h], ex);
            }
        } else if (j < deg){
            int e = perm[e0 + j];
            int src = ei[e], rt = et[e];
            float4 k4 = *(const float4*)&ws[O_AK + (long)src*16 + rt*4];
            float al[4] = {lrelu_f(aq[rt*4+0]+k4.x), lrelu_f(aq[rt*4+1]+k4.y),
                           lrelu_f(aq[rt*4+2]+k4.z), lrelu_f(aq[rt*4+3]+k4.w)};
            #pragma unroll
            for (int h = 0; h < 4; h++) atomicAdd(&den[h], expf(al[h]-amax[h]));
        }
    }
    __syncthreads();
    // pass 3: 4-way unrolled coalesced gather (independent loads for MLP)
    int d = tid;
    const unsigned short* xw2 = (const unsigned short*)(ws + O_XW2);
    float a0=0.f, a1=0.f, a2=0.f, a3=0.f;
    int mdeg = min(deg, EMAX);
    int j = 0;
    for (; j + 4 <= mdeg; j += 4){
        long s0 = esrt[j], s1 = esrt[j+1], s2 = esrt[j+2], s3 = esrt[j+3];
        u16x4 v0 = *(const u16x4*)(xw2 + s0*512 + (d << 2));
        u16x4 v1 = *(const u16x4*)(xw2 + s1*512 + (d << 2));
        u16x4 v2 = *(const u16x4*)(xw2 + s2*512 + (d << 2));
        u16x4 v3 = *(const u16x4*)(xw2 + s3*512 + (d << 2));
        a0 += exc[j  ][0]*bf2f(v0[0]); a1 += exc[j  ][1]*bf2f(v0[1]);
        a2 += exc[j  ][2]*bf2f(v0[2]); a3 += exc[j  ][3]*bf2f(v0[3]);
        a0 += exc[j+1][0]*bf2f(v1[0]); a1 += exc[j+1][1]*bf2f(v1[1]);
        a2 += exc[j+1][2]*bf2f(v1[2]); a3 += exc[j+1][3]*bf2f(v1[3]);
        a0 += exc[j+2][0]*bf2f(v2[0]); a1 += exc[j+2][1]*bf2f(v2[1]);
        a2 += exc[j+2][2]*bf2f(v2[2]); a3 += exc[j+2][3]*bf2f(v2[3]);
        a0 += exc[j+3][0]*bf2f(v3[0]); a1 += exc[j+3][1]*bf2f(v3[1]);
        a2 += exc[j+3][2]*bf2f(v3[2]); a3 += exc[j+3][3]*bf2f(v3[3]);
    }
    for (; j < mdeg; j++){
        long sr = esrt[j];
        u16x4 v = *(const u16x4*)(xw2 + sr*512 + (d << 2));
        a0 += exc[j][0]*bf2f(v[0]); a1 += exc[j][1]*bf2f(v[1]);
        a2 += exc[j][2]*bf2f(v[2]); a3 += exc[j][3]*bf2f(v[3]);
    }
    for (j = EMAX; j < deg; j++){
        int e = perm[e0 + j];
        int src = ei[e], rt = et[e];
        float4 k4 = *(const float4*)&ws[O_AK + (long)src*16 + rt*4];
        float e0h = expf(lrelu_f(aq[rt*4+0]+k4.x)-amax[0]);
        float e1h = expf(lrelu_f(aq[rt*4+1]+k4.y)-amax[1]);
        float e2h = expf(lrelu_f(aq[rt*4+2]+k4.z)-amax[2]);
        float e3h = expf(lrelu_f(aq[rt*4+3]+k4.w)-amax[3]);
        u16x4 v = *(const u16x4*)(xw2 + ((long)src*4 + rt)*512 + (d << 2));
        a0 += e0h*bf2f(v[0]); a1 += e1h*bf2f(v[1]);
        a2 += e2h*bf2f(v[2]); a3 += e3h*bf2f(v[3]);
    }
    float rd0 = den[0] > 0.f ? 0.25f/den[0] : 0.f;
    float rd1 = den[1] > 0.f ? 0.25f/den[1] : 0.f;
    float rd2 = den[2] > 0.f ? 0.25f/den[2] : 0.f;
    float rd3 = den[3] > 0.f ? 0.25f/den[3] : 0.f;
    float v = a0*rd0 + a1*rd1 + a2*rd2 + a3*rd3;
    ws[O_H2 + (long)n*128 + d] = selu_f(v + ws[O_B2 + d]);
}

// ---------------- fused tail: pool + cos + ff1 + ff2 + dueling head ----------------
__global__ void k_tail(float* ws, void* d_out, const void* taus_raw){
    __shared__ float g[128];
    __shared__ float cs[64];
    __shared__ float row0[128], row1[128], row2[128];
    __shared__ float advs[12];
    int b = blockIdx.x, t = threadIdx.x;
    float s = 0.f;
    for (int j = 0; j < GN; j++) s += ws[O_H2 + ((long)b*GN + j)*128 + t];
    g[t] = s;
    int bf = ((const int*)ws)[0];
    for (int tt = 0; tt < TT; tt++){
        int bt = b*TT + tt;
        __syncthreads();
        if (t < 64){
            float tau = ws[O_TAU + bt];
            cs[t] = cosf(tau * (3.14159265358979323846f * (float)(t + 1)));
        }
        __syncthreads();
        {
            const float* cw = ws + O_CW + (long)t*64;
            float z = ws[O_CB + t];
            for (int c = 0; c < 64; c++) z += cs[c]*cw[c];
            row0[t] = g[t] * fmaxf(z, 0.f);
        }
        __syncthreads();
        {
            const float* W = ws + O_CF1W + (long)t*128;
            float s1 = ws[O_CF1B + t];
            for (int i = 0; i < 128; i++) s1 += row0[i]*W[i];
            row1[t] = selu_f(s1);
        }
        __syncthreads();
        {
            const float* W = ws + O_CF2W + (long)t*128;
            float s2 = ws[O_CF2B + t];
            for (int i = 0; i < 128; i++) s2 += row1[i]*W[i];
            row2[t] = selu_f(s2);
        }
        __syncthreads();
        if (t < 11){
            const float* W = (t < 10) ? (ws + O_CAW + (long)t*128) : (ws + O_CVW);
            float sa = (t < 10) ? ws[O_CAB + t] : ws[O_CVB];
            for (int i = 0; i < 128; i++) sa += row2[i]*W[i];
            advs[t] = sa;
        }
        __syncthreads();
        if (t == 0){
            float m = 0.f;
            #pragma unroll
            for (int a = 0; a < 10; a++) m += advs[a];
            m *= 0.1f;
            float val = advs[10];
            if (bf){
                __hip_bfloat16* out = (__hip_bfloat16*)d_out;
                for (int a = 0; a < 10; a++) out[(long)bt*10 + a] = __float2bfloat16(val + advs[a] - m);
                ((unsigned short*)d_out)[16000 + bt] = ((const unsigned short*)taus_raw)[bt];
            } else {
                float* out = (float*)d_out;
                for (int a = 0; a < 10; a++) out[(long)bt*10 + a] = val + advs[a] - m;
                out[16000 + bt] = ((const float*)taus_raw)[bt];
            }
        }
    }
}

// ---------------- launch ----------------
extern "C" void kernel_launch(void* const* d_in, const int* in_sizes, int n_in,
                              void* d_out, int out_size, void* d_ws, size_t ws_size,
                              hipStream_t stream){
    (void)in_sizes; (void)n_in; (void)out_size; (void)ws_size;
    float* ws = (float*)d_ws;
    const int* ei = (const int*)d_in[1];
    const int* et = (const int*)d_in[2];

    hipMemsetAsync(ws + O_DEG, 0, (size_t)(2*NN)*4, stream);

    k_pre<<<626, 256, 0, stream>>>((const unsigned short*)d_in[3], ei, ws);
    k_scan<<<1, 256, 0, stream>>>(ws);

    ConvArgs ca;
    static const long conv_o[38] = {
        O_X, -1, -1, O_TAU, O_W1, O_Q1, O_K1, O_B1, O_W2, O_Q2, O_K2, O_B2, O_CW, O_CB,
        O_F1W, O_F1B, O_F1SW, O_F1SB, O_F1EW, O_F1EB,
        O_F2W, O_F2B, O_F2SW, O_F2SB, O_F2EW, O_F2EB,
        O_AW, O_AB, O_ASW, O_ASB, O_AEW, O_AEB,
        O_VW, O_VB, O_VSW, O_VSB, O_VEW, O_VEB };
    static const int conv_n[38] = {
        40000, 0, 0, 1600, 4096, 2048, 2048, 128, 262144, 2048, 2048, 128, 8192, 128,
        16384, 128, 16384, 128, 16384, 128,
        16384, 128, 16384, 128, 16384, 128,
        1280, 10, 1280, 10, 1280, 10,
        128, 1, 128, 1, 128, 1 };
    for (int i = 0; i < 38; i++){ ca.src[i] = d_in[i]; ca.off[i] = conv_o[i]; ca.n[i] = conv_n[i]; }
    k_conv_scatter<<<dim3(625, 39), 256, 0, stream>>>(ca, ei, ws);

    k_prep<<<dim3(1024, 4), 256, 0, stream>>>(ws);

    k_node1<<<20000, 128, 0, stream>>>(ei, et, ws);

    k_xw2_mfma<<<dim3(157, 16), 256, 0, stream>>>(ws);
    k_aqk<<<1250, 256, 0, stream>>>(ws);
    k_node2<<<20000, 128, 0, stream>>>(ei, et, ws);

    k_tail<<<200, 128, 0, stream>>>(ws, d_out, d_in[3]);
}

// Round 7
// 243.787 us; speedup vs baseline: 1.0824x; 1.0824x over previous
//
#include <hip/hip_runtime.h>
#include <hip/hip_bf16.h>

// ---------------- problem constants ----------------
constexpr long NN = 20000;   // nodes
constexpr long NE = 160000;  // edges
constexpr long BB = 200;     // graphs
constexpr long TT = 8;       // taus
constexpr long GN = 100;     // nodes per graph

// ---------------- ws layout (f32 element offsets) ----------------
constexpr long O_FLAG = 0;                                      // int mode flag
constexpr long O_X    = 16;                 constexpr long N_X   = 40000;
constexpr long O_TAU  = O_X + N_X;          constexpr long N_TAU = 1600;
constexpr long O_W1   = O_TAU + N_TAU;      constexpr long N_W1  = 4096;
constexpr long O_Q1   = O_W1 + N_W1;        constexpr long N_Q   = 2048;
constexpr long O_K1   = O_Q1 + N_Q;
constexpr long O_B1   = O_K1 + N_Q;         constexpr long N_B   = 128;
constexpr long O_W2   = O_B1 + N_B;         constexpr long N_W2  = 262144;
constexpr long O_Q2   = O_W2 + N_W2;
constexpr long O_K2   = O_Q2 + N_Q;
constexpr long O_B2   = O_K2 + N_Q;
constexpr long O_CW   = O_B2 + N_B;         constexpr long N_CW  = 8192;
constexpr long O_CB   = O_CW + N_CW;
constexpr long O_F1W  = O_CB + N_B;         constexpr long N_FW  = 16384;
constexpr long O_F1B  = O_F1W + N_FW;
constexpr long O_F1SW = O_F1B + N_B;
constexpr long O_F1SB = O_F1SW + N_FW;
constexpr long O_F1EW = O_F1SB + N_B;
constexpr long O_F1EB = O_F1EW + N_FW;
constexpr long O_F2W  = O_F1EB + N_B;
constexpr long O_F2B  = O_F2W + N_FW;
constexpr long O_F2SW = O_F2B + N_B;
constexpr long O_F2SB = O_F2SW + N_FW;
constexpr long O_F2EW = O_F2SB + N_B;
constexpr long O_F2EB = O_F2EW + N_FW;
constexpr long O_AW   = O_F2EB + N_B;       constexpr long N_AW  = 1280;
constexpr long O_AB   = O_AW + N_AW;        constexpr long N_AB  = 16;  // 10 used
constexpr long O_ASW  = O_AB + N_AB;
constexpr long O_ASB  = O_ASW + N_AW;
constexpr long O_AEW  = O_ASB + N_AB;
constexpr long O_AEB  = O_AEW + N_AW;
constexpr long O_VW   = O_AEB + N_AB;       constexpr long N_VW  = 128;
constexpr long O_VB   = O_VW + N_VW;        constexpr long N_VB  = 16;  // 1 used
constexpr long O_VSW  = O_VB + N_VB;
constexpr long O_VSB  = O_VSW + N_VW;
constexpr long O_VEW  = O_VSB + N_VB;
constexpr long O_VEB  = O_VEW + N_VW;
// derived
constexpr long O_WQ1  = O_VEB + N_VB;       // [4][2][4] = 32  (r*8 + i*4 + h)
constexpr long O_WK1  = O_WQ1 + 32;
constexpr long O_WQ2  = O_WK1 + 32;         // [4][128][4] = 2048
constexpr long O_WK2  = O_WQ2 + 2048;
constexpr long O_CF1W = O_WK2 + 2048;       // combined noisy weights
constexpr long O_CF1B = O_CF1W + N_FW;
constexpr long O_CF2W = O_CF1B + N_B;
constexpr long O_CF2B = O_CF2W + N_FW;
constexpr long O_CAW  = O_CF2B + N_B;
constexpr long O_CAB  = O_CAW + N_AW;
constexpr long O_CVW  = O_CAB + N_AB;
constexpr long O_CVB  = O_CVW + N_VW;
constexpr long O_AL1  = O_CVB + N_VB;       // (spacer)
constexpr long O_AL2  = O_AL1 + NE*4;
constexpr long O_H1   = O_AL2 + NE*4;       // (spacer)
constexpr long O_H2   = O_H1 + NN*128;
constexpr long O_G    = O_H2 + NN*128;      // [200][128]
constexpr long O_Z0   = O_G + BB*128;
constexpr long O_Z1   = O_Z0 + BB*TT*128;
constexpr long O_Z2   = O_Z1 + BB*TT*128;
// CSR region
constexpr long O_AGG1 = O_Z2 + BB*TT*128;
constexpr long O_DEG  = O_AGG1;             // [NN] int
constexpr long O_CUR  = O_DEG + NN;         // [NN] int
constexpr long O_ROWP = O_CUR + NN;         // [NN+1] int (+pad)
constexpr long O_PERM = O_ROWP + NN + 8;    // [NE] int
constexpr long O_AGG2 = O_AGG1 + NN*128;
constexpr long O_DEN1 = O_AGG2 + NN*128;
constexpr long O_DEN2 = O_DEN1 + NN*4;
constexpr long O_AMAX1= O_DEN2 + NN*4;
constexpr long O_AMAX2= O_AMAX1 + NN*4;
// bf16 xw2 table [N][4][512] — inner 512 ordered d*4+h (viewed as u16)
constexpr long O_XW2  = O_AMAX2 + NN*4;
constexpr long O_END_TABLE = O_XW2 + (NN*4*512)/2;
// MFMA-path extras
constexpr long MPAD   = 20096;
constexpr long O_H1B  = O_END_TABLE;                  // [20096][128] bf16
constexpr long O_W2BT = O_H1B + (MPAD*128)/2;         // [2048][128] bf16, row-permuted
constexpr long O_END2 = O_W2BT + (2048L*128)/2;
// AQ/AK tables: [N][16] f32, idx = r*4+h
constexpr long O_AQ   = O_END2;
constexpr long O_AK   = O_AQ + NN*16;
constexpr long O_END3 = O_AK + NN*16;

constexpr int EMAX = 128;

#define DEVFN __device__ __forceinline__

typedef __attribute__((ext_vector_type(8))) short bf16x8;
typedef __attribute__((ext_vector_type(4))) float f32x4;
typedef __attribute__((ext_vector_type(4))) unsigned short u16x4;

DEVFN float selu_f(float x){ return 1.0507009873554805f * (x > 0.f ? x : 1.6732632423543772f * expm1f(x)); }
DEVFN float lrelu_f(float x){ return x >= 0.f ? x : 0.2f * x; }
DEVFN float bf2f(unsigned short u){ return __uint_as_float(((unsigned)u) << 16); }

// ---------------- fused detect + histogram ----------------
__global__ void k_pre(const unsigned short* taus_u16, const int* ei, float* ws){
    if (blockIdx.x == 0){
        if (threadIdx.x == 0){
            int bf = 1;
            for (int i = 0; i < 128; i++) if (taus_u16[i] > 0x3F80u){ bf = 0; break; }
            ((int*)ws)[0] = bf;
        }
        return;
    }
    long e = (long)(blockIdx.x - 1)*blockDim.x + threadIdx.x;
    if (e >= NE) return;
    atomicAdd((int*)(ws + O_DEG) + ei[NE + e], 1);
}

__global__ void k_scan(float* ws){
    const int* deg = (const int*)(ws + O_DEG);
    int* rowp = (int*)(ws + O_ROWP);
    __shared__ int part[256];
    int tid = threadIdx.x;
    int base = tid * 79;
    int n = 0; if (base < NN) n = min(79, (int)NN - base);
    int s = 0;
    for (int i = 0; i < n; i++) s += deg[base + i];
    part[tid] = s;
    __syncthreads();
    if (tid == 0){
        int acc = 0;
        for (int i = 0; i < 256; i++){ int t = part[i]; part[i] = acc; acc += t; }
    }
    __syncthreads();
    int acc = part[tid];
    for (int i = 0; i < n; i++){ rowp[base + i] = acc; acc += deg[base + i]; }
    if (tid == 0) rowp[NN] = (int)NE;
}

// ---------------- fused convert (y<38) + CSR scatter (y=38) ----------------
struct ConvArgs { const void* src[38]; long off[38]; int n[38]; };

__global__ void k_conv_scatter(ConvArgs a, const int* ei, float* ws){
    int y = blockIdx.y;
    if (y == 38){
        long e = (long)blockIdx.x*blockDim.x + threadIdx.x;
        if (e >= NE) return;
        int dst = ei[NE + e];
        int pos = atomicAdd((int*)(ws + O_CUR) + dst, 1);
        ((int*)(ws + O_PERM))[((const int*)(ws + O_ROWP))[dst] + pos] = (int)e;
        return;
    }
    long off = a.off[y];
    if (off < 0) return;
    const void* s = a.src[y];
    int n = a.n[y];
    int bf = ((const int*)ws)[0];
    for (int i = blockIdx.x*blockDim.x + threadIdx.x; i < n; i += gridDim.x*blockDim.x){
        float v;
        if (bf){ unsigned short u = ((const unsigned short*)s)[i]; v = bf2f(u); }
        else   { v = ((const float*)s)[i]; }
        ws[off + i] = v;
    }
}

// ---------------- fused prep: fold + noisy + w2b + zpad ----------------
__global__ void k_prep(float* ws){
    int phase = blockIdx.y;
    int idx = blockIdx.x*blockDim.x + threadIdx.x;
    if (phase == 0){
        if (idx >= 4160) return;
        long wsrc, qsrc, dst; int ri, h;
        if (idx < 64){
            int t = idx & 31; h = t & 3; ri = t >> 2;
            wsrc = O_W1 + (long)ri*512;
            qsrc = (idx < 32) ? O_Q1 : O_K1;
            dst  = ((idx < 32) ? O_WQ1 : O_WK1) + t;
        } else {
            int t = (idx - 64) & 2047; h = t & 3; ri = t >> 2;
            wsrc = O_W2 + (long)ri*512;
            qsrc = (idx < 2112) ? O_Q2 : O_K2;
            dst  = ((idx < 2112) ? O_WQ2 : O_WK2) + t;
        }
        const float* W = ws + wsrc;
        const float* Q = ws + qsrc;
        float s = 0.f;
        for (int o = 0; o < 512; o++) s += W[o] * Q[o*4 + h];
        ws[dst] = s;
    } else if (phase == 1){
        const long tw[8] = {O_F1W,O_F2W,O_AW,O_VW, O_F1B,O_F2B,O_AB,O_VB};
        const long ts[8] = {O_F1SW,O_F2SW,O_ASW,O_VSW, O_F1SB,O_F2SB,O_ASB,O_VSB};
        const long te[8] = {O_F1EW,O_F2EW,O_AEW,O_VEW, O_F1EB,O_F2EB,O_AEB,O_VEB};
        const long td[8] = {O_CF1W,O_CF2W,O_CAW,O_CVW, O_CF1B,O_CF2B,O_CAB,O_CVB};
        const int  tn[8] = {16384,16384,1280,128, 128,128,10,1};
        const int  tb[8] = {0,16384,32768,34048, 34176,34304,34432,34442};
        int total = 34443;
        for (int i = idx; i < total; i += gridDim.x*blockDim.x){
            int t = 0;
            #pragma unroll
            for (int q = 1; q < 8; q++) if (i >= tb[q]) t = q;
            int j = i - tb[t];
            if (j < tn[t]) ws[td[t] + j] = ws[tw[t] + j] + ws[ts[t] + j]*ws[te[t] + j];
        }
    } else if (phase == 2){
        // W2 -> Bt row-permuted bf16: row n' = r*512 + d*4 + h holds W2[r][:,h*128+d]
        if (idx >= 262144) return;
        int np = idx & 2047, k = idx >> 11;
        int r = np >> 9, q = np & 511, d = q >> 2, h = q & 3;
        float v = ws[O_W2 + (long)r*65536 + (long)k*512 + h*128 + d];
        ((__hip_bfloat16*)(ws + O_W2BT))[(long)np*128 + k] = __float2bfloat16(v);
    } else {
        if (idx < 6144) ws[O_H1B + (20000L*128)/2 + idx] = 0.f;
    }
}

// ---------------- fused layer-1 node kernel (bf16 h1 output only) ----------------
__global__ void k_node1(const int* ei, const int* et, float* ws){
    __shared__ float wqk[64];
    __shared__ float alc[EMAX][4];
    __shared__ float xsc[EMAX][2];
    __shared__ int   rtc[EMAX];
    __shared__ float sacc[4][4][2];
    __shared__ float den[4], amax[4];
    __shared__ float mred[2][4];
    int n = blockIdx.x, tid = threadIdx.x;
    const int* rowp = (const int*)(ws + O_ROWP);
    const int* perm = (const int*)(ws + O_PERM);
    int e0 = rowp[n], deg = rowp[n+1] - e0;
    if (tid < 64) wqk[tid] = ws[O_WQ1 + tid];
    if (tid < 32) ((float*)sacc)[tid] = 0.f;
    if (tid < 4) den[tid] = 0.f;
    float xd0 = ws[O_X + (long)n*2], xd1 = ws[O_X + (long)n*2 + 1];
    __syncthreads();
    float mx[4] = {-3.0e38f,-3.0e38f,-3.0e38f,-3.0e38f};
    for (int j0 = 0; j0 < deg; j0 += 128){
        int j = j0 + tid;
        if (j < deg){
            int e = perm[e0 + j];
            int src = ei[e], rt = et[e];
            float xs0 = ws[O_X + (long)src*2], xs1 = ws[O_X + (long)src*2 + 1];
            const float* Wq = wqk + rt*8;
            const float* Wk = wqk + 32 + rt*8;
            #pragma unroll
            for (int h = 0; h < 4; h++){
                float a = lrelu_f(xd0*Wq[h] + xd1*Wq[4+h] + xs0*Wk[h] + xs1*Wk[4+h]);
                if (j < EMAX) alc[j][h] = a;
                mx[h] = fmaxf(mx[h], a);
            }
            if (j < EMAX){ xsc[j][0] = xs0; xsc[j][1] = xs1; rtc[j] = rt; }
        }
    }
    #pragma unroll
    for (int off = 32; off > 0; off >>= 1)
        #pragma unroll
        for (int h = 0; h < 4; h++) mx[h] = fmaxf(mx[h], __shfl_xor(mx[h], off));
    if ((tid & 63) == 0)
        #pragma unroll
        for (int h = 0; h < 4; h++) mred[tid >> 6][h] = mx[h];
    __syncthreads();
    if (tid < 4) amax[tid] = fmaxf(mred[0][tid], mred[1][tid]);
    __syncthreads();
    for (int j0 = 0; j0 < deg; j0 += 128){
        int j = j0 + tid;
        if (j < deg){
            float al[4], xs0, xs1; int rt;
            if (j < EMAX){
                #pragma unroll
                for (int h = 0; h < 4; h++) al[h] = alc[j][h];
                xs0 = xsc[j][0]; xs1 = xsc[j][1]; rt = rtc[j];
            } else {
                int e = perm[e0 + j];
                int src = ei[e]; rt = et[e];
                xs0 = ws[O_X + (long)src*2]; xs1 = ws[O_X + (long)src*2 + 1];
                const float* Wq = wqk + rt*8;
                const float* Wk = wqk + 32 + rt*8;
                #pragma unroll
                for (int h = 0; h < 4; h++)
                    al[h] = lrelu_f(xd0*Wq[h] + xd1*Wq[4+h] + xs0*Wk[h] + xs1*Wk[4+h]);
            }
            #pragma unroll
            for (int h = 0; h < 4; h++){
                float ex = expf(al[h] - amax[h]);
                atomicAdd(&den[h], ex);
                atomicAdd(&sacc[rt][h][0], ex*xs0);
                atomicAdd(&sacc[rt][h][1], ex*xs1);
            }
        }
    }
    __syncthreads();
    int d = tid;
    float rden[4];
    #pragma unroll
    for (int h = 0; h < 4; h++) rden[h] = den[h] > 0.f ? 0.25f/den[h] : 0.f;
    float v = 0.f;
    #pragma unroll
    for (int r = 0; r < 4; r++)
        #pragma unroll
        for (int h = 0; h < 4; h++){
            float w0 = ws[O_W1 + r*1024 +        h*128 + d];
            float w1 = ws[O_W1 + r*1024 + 512  + h*128 + d];
            v += rden[h]*(w0*sacc[r][h][0] + w1*sacc[r][h][1]);
        }
    float out = selu_f(v + ws[O_B1 + d]);
    ((__hip_bfloat16*)(ws + O_H1B))[(long)n*128 + d] = __float2bfloat16(out);
}

// ---------------- AQ/AK tables (from bf16 h1) ----------------
__global__ void k_aqk(float* ws){
    __shared__ float wq[128*16];
    __shared__ float wk[128*16];
    __shared__ float hl[16][129];
    int tid = threadIdx.x;
    long nb = (long)blockIdx.x * 16;
    const unsigned short* h1b = (const unsigned short*)(ws + O_H1B);
    #pragma unroll
    for (int c = 0; c < 8; c++){
        int idx = tid + c*256;
        int i = idx >> 4, o = idx & 15;
        int r = o >> 2, h = o & 3;
        wq[i*16 + o] = ws[O_WQ2 + r*512 + i*4 + h];
        wk[i*16 + o] = ws[O_WK2 + r*512 + i*4 + h];
        hl[idx >> 7][idx & 127] = bf2f(h1b[nb*128 + idx]);
    }
    __syncthreads();
    int j = tid >> 4, o = tid & 15;
    float aq = 0.f, ak = 0.f;
    #pragma unroll 4
    for (int i = 0; i < 128; i++){
        float hv = hl[j][i];
        aq += hv * wq[i*16 + o];
        ak += hv * wk[i*16 + o];
    }
    ws[O_AQ + (nb + j)*16 + o] = aq;
    ws[O_AK + (nb + j)*16 + o] = ak;
}

// ---------------- xw2 = h1 @ W2 via MFMA (B rows pre-permuted) ----------------
__global__ void k_xw2_mfma(float* ws){
    __shared__ __align__(16) unsigned short Ash[128*128];
    __shared__ __align__(16) unsigned short Bsh[128*128];
    const unsigned short* h1b  = (const unsigned short*)(ws + O_H1B);
    const unsigned short* w2bt = (const unsigned short*)(ws + O_W2BT);
    long bm = (long)blockIdx.x * 128;
    long bn = (long)blockIdx.y * 128;
    int tid = threadIdx.x;
    char* Ac = (char*)Ash; char* Bc = (char*)Bsh;
    #pragma unroll
    for (int i = 0; i < 8; i++){
        int c = tid + i*256;
        int row = c >> 4, kb = (c & 15) * 16;
        int off = row*256 + (kb ^ ((row & 7) << 4));
        *(bf16x8*)(Ac + off) = *(const bf16x8*)&h1b [(bm + row)*128 + (c & 15)*8];
        *(bf16x8*)(Bc + off) = *(const bf16x8*)&w2bt[(bn + row)*128 + (c & 15)*8];
    }
    __syncthreads();
    int w = tid >> 6, lane = tid & 63;
    int wm = (w >> 1) * 64, wn = (w & 1) * 64;
    int r16 = lane & 15, kq = lane >> 4;
    f32x4 acc[4][4] = {};
    #pragma unroll
    for (int ks = 0; ks < 4; ks++){
        int kbyte = ks*64 + kq*16;
        bf16x8 a[4], b[4];
        #pragma unroll
        for (int m = 0; m < 4; m++){
            int row = wm + m*16 + r16;
            a[m] = *(const bf16x8*)(Ac + row*256 + (kbyte ^ ((row & 7) << 4)));
        }
        #pragma unroll
        for (int n = 0; n < 4; n++){
            int row = wn + n*16 + r16;
            b[n] = *(const bf16x8*)(Bc + row*256 + (kbyte ^ ((row & 7) << 4)));
        }
        #pragma unroll
        for (int m = 0; m < 4; m++)
            #pragma unroll
            for (int n = 0; n < 4; n++)
                acc[m][n] = __builtin_amdgcn_mfma_f32_16x16x32_bf16(a[m], b[n], acc[m][n], 0, 0, 0);
    }
    __hip_bfloat16* xb = (__hip_bfloat16*)(ws + O_XW2);
    #pragma unroll
    for (int m = 0; m < 4; m++){
        long gr0 = bm + wm + m*16 + kq*4;
        #pragma unroll
        for (int j = 0; j < 4; j++){
            long gr = gr0 + j;
            if (gr < NN){
                #pragma unroll
                for (int n = 0; n < 4; n++){
                    long gc = bn + wn + n*16 + r16;
                    xb[gr*2048 + gc] = __float2bfloat16(acc[m][n][j]);
                }
            }
        }
    }
}

// ---------------- fused layer-2 node kernel (4-way unrolled gather) ----------------
__global__ void k_node2(const int* ei, const int* et, float* ws){
    __shared__ float aq[16];
    __shared__ float exc[EMAX][4];
    __shared__ int   esrt[EMAX];
    __shared__ float den[4], amax[4];
    __shared__ float mred[2][4];
    int n = blockIdx.x, tid = threadIdx.x;
    const int* rowp = (const int*)(ws + O_ROWP);
    const int* perm = (const int*)(ws + O_PERM);
    int e0 = rowp[n], deg = rowp[n+1] - e0;
    if (tid < 16) aq[tid] = ws[O_AQ + (long)n*16 + tid];
    if (tid < 4) den[tid] = 0.f;
    __syncthreads();
    float mx[4] = {-3.0e38f,-3.0e38f,-3.0e38f,-3.0e38f};
    for (int j0 = 0; j0 < deg; j0 += 128){
        int j = j0 + tid;
        if (j < deg){
            int e = perm[e0 + j];
            int src = ei[e], rt = et[e];
            float4 k4 = *(const float4*)&ws[O_AK + (long)src*16 + rt*4];
            float al0 = lrelu_f(aq[rt*4+0] + k4.x);
            float al1 = lrelu_f(aq[rt*4+1] + k4.y);
            float al2 = lrelu_f(aq[rt*4+2] + k4.z);
            float al3 = lrelu_f(aq[rt*4+3] + k4.w);
            if (j < EMAX){
                exc[j][0]=al0; exc[j][1]=al1; exc[j][2]=al2; exc[j][3]=al3;
                esrt[j] = src*4 + rt;
            }
            mx[0]=fmaxf(mx[0],al0); mx[1]=fmaxf(mx[1],al1);
            mx[2]=fmaxf(mx[2],al2); mx[3]=fmaxf(mx[3],al3);
        }
    }
    #pragma unroll
    for (int off = 32; off > 0; off >>= 1)
        #pragma unroll
        for (int h = 0; h < 4; h++) mx[h] = fmaxf(mx[h], __shfl_xor(mx[h], off));
    if ((tid & 63) == 0)
        #pragma unroll
        for (int h = 0; h < 4; h++) mred[tid >> 6][h] = mx[h];
    __syncthreads();
    if (tid < 4) amax[tid] = fmaxf(mred[0][tid], mred[1][tid]);
    __syncthreads();
    for (int j0 = 0; j0 < deg; j0 += 128){
        int j = j0 + tid;
        if (j < deg && j < EMAX){
            #pragma unroll
            for (int h = 0; h < 4; h++){
                float ex = expf(exc[j][h] - amax[h]);
                exc[j][h] = ex;
                atomicAdd(&den[h], ex);
            }
        } else if (j < deg){
            int e = perm[e0 + j];
            int src = ei[e], rt = et[e];
            float4 k4 = *(const float4*)&ws[O_AK + (long)src*16 + rt*4];
            float al[4] = {lrelu_f(aq[rt*4+0]+k4.x), lrelu_f(aq[rt*4+1]+k4.y),
                           lrelu_f(aq[rt*4+2]+k4.z), lrelu_f(aq[rt*4+3]+k4.w)};
            #pragma unroll
            for (int h = 0; h < 4; h++) atomicAdd(&den[h], expf(al[h]-amax[h]));
        }
    }
    __syncthreads();
    // pass 3: 4-way unrolled coalesced gather (independent loads for MLP)
    int d = tid;
    const unsigned short* xw2 = (const unsigned short*)(ws + O_XW2);
    float a0=0.f, a1=0.f, a2=0.f, a3=0.f;
    int mdeg = min(deg, EMAX);
    int j = 0;
    for (; j + 4 <= mdeg; j += 4){
        long s0 = esrt[j], s1 = esrt[j+1], s2 = esrt[j+2], s3 = esrt[j+3];
        u16x4 v0 = *(const u16x4*)(xw2 + s0*512 + (d << 2));
        u16x4 v1 = *(const u16x4*)(xw2 + s1*512 + (d << 2));
        u16x4 v2 = *(const u16x4*)(xw2 + s2*512 + (d << 2));
        u16x4 v3 = *(const u16x4*)(xw2 + s3*512 + (d << 2));
        a0 += exc[j  ][0]*bf2f(v0[0]); a1 += exc[j  ][1]*bf2f(v0[1]);
        a2 += exc[j  ][2]*bf2f(v0[2]); a3 += exc[j  ][3]*bf2f(v0[3]);
        a0 += exc[j+1][0]*bf2f(v1[0]); a1 += exc[j+1][1]*bf2f(v1[1]);
        a2 += exc[j+1][2]*bf2f(v1[2]); a3 += exc[j+1][3]*bf2f(v1[3]);
        a0 += exc[j+2][0]*bf2f(v2[0]); a1 += exc[j+2][1]*bf2f(v2[1]);
        a2 += exc[j+2][2]*bf2f(v2[2]); a3 += exc[j+2][3]*bf2f(v2[3]);
        a0 += exc[j+3][0]*bf2f(v3[0]); a1 += exc[j+3][1]*bf2f(v3[1]);
        a2 += exc[j+3][2]*bf2f(v3[2]); a3 += exc[j+3][3]*bf2f(v3[3]);
    }
    for (; j < mdeg; j++){
        long sr = esrt[j];
        u16x4 v = *(const u16x4*)(xw2 + sr*512 + (d << 2));
        a0 += exc[j][0]*bf2f(v[0]); a1 += exc[j][1]*bf2f(v[1]);
        a2 += exc[j][2]*bf2f(v[2]); a3 += exc[j][3]*bf2f(v[3]);
    }
    for (j = EMAX; j < deg; j++){
        int e = perm[e0 + j];
        int src = ei[e], rt = et[e];
        float4 k4 = *(const float4*)&ws[O_AK + (long)src*16 + rt*4];
        float e0h = expf(lrelu_f(aq[rt*4+0]+k4.x)-amax[0]);
        float e1h = expf(lrelu_f(aq[rt*4+1]+k4.y)-amax[1]);
        float e2h = expf(lrelu_f(aq[rt*4+2]+k4.z)-amax[2]);
        float e3h = expf(lrelu_f(aq[rt*4+3]+k4.w)-amax[3]);
        u16x4 v = *(const u16x4*)(xw2 + ((long)src*4 + rt)*512 + (d << 2));
        a0 += e0h*bf2f(v[0]); a1 += e1h*bf2f(v[1]);
        a2 += e2h*bf2f(v[2]); a3 += e3h*bf2f(v[3]);
    }
    float rd0 = den[0] > 0.f ? 0.25f/den[0] : 0.f;
    float rd1 = den[1] > 0.f ? 0.25f/den[1] : 0.f;
    float rd2 = den[2] > 0.f ? 0.25f/den[2] : 0.f;
    float rd3 = den[3] > 0.f ? 0.25f/den[3] : 0.f;
    float v = a0*rd0 + a1*rd1 + a2*rd2 + a3*rd3;
    ws[O_H2 + (long)n*128 + d] = selu_f(v + ws[O_B2 + d]);
}

// ---------------- global add pool ----------------
__global__ void k_pool(float* ws){
    int b = blockIdx.x, d = threadIdx.x;
    float s = 0.f;
    for (int j = 0; j < GN; j++) s += ws[O_H2 + ((long)b*GN + j)*128 + d];
    ws[O_G + (long)b*128 + d] = s;
}

// ---------------- fused tail: cos embed + z + ff1 + ff2 + dueling head (1600 blocks) --------
__global__ void k_tail(float* ws, void* d_out, const void* taus_raw){
    __shared__ float cs[64];
    __shared__ float row0[128], row1[128], row2[128];
    __shared__ float advs[12];
    int bt = blockIdx.x, t = threadIdx.x;
    int b = bt >> 3;
    if (t < 64){
        float tau = ws[O_TAU + bt];
        cs[t] = cosf(tau * (3.14159265358979323846f * (float)(t + 1)));
    }
    __syncthreads();
    {
        const float* cw = ws + O_CW + (long)t*64;
        float s = ws[O_CB + t];
        for (int c = 0; c < 64; c++) s += cs[c]*cw[c];
        s = fmaxf(s, 0.f);
        row0[t] = ws[O_G + (long)b*128 + t] * s;
    }
    __syncthreads();
    {
        const float* W = ws + O_CF1W + (long)t*128;
        float s = ws[O_CF1B + t];
        for (int i = 0; i < 128; i++) s += row0[i]*W[i];
        row1[t] = selu_f(s);
    }
    __syncthreads();
    {
        const float* W = ws + O_CF2W + (long)t*128;
        float s = ws[O_CF2B + t];
        for (int i = 0; i < 128; i++) s += row1[i]*W[i];
        row2[t] = selu_f(s);
    }
    __syncthreads();
    if (t < 11){
        const float* W = (t < 10) ? (ws + O_CAW + (long)t*128) : (ws + O_CVW);
        float s = (t < 10) ? ws[O_CAB + t] : ws[O_CVB];
        for (int i = 0; i < 128; i++) s += row2[i]*W[i];
        advs[t] = s;
    }
    __syncthreads();
    if (t == 0){
        float m = 0.f;
        #pragma unroll
        for (int a = 0; a < 10; a++) m += advs[a];
        m *= 0.1f;
        float val = advs[10];
        int bf = ((const int*)ws)[0];
        if (bf){
            __hip_bfloat16* out = (__hip_bfloat16*)d_out;
            for (int a = 0; a < 10; a++) out[(long)bt*10 + a] = __float2bfloat16(val + advs[a] - m);
            ((unsigned short*)d_out)[16000 + bt] = ((const unsigned short*)taus_raw)[bt];
        } else {
            float* out = (float*)d_out;
            for (int a = 0; a < 10; a++) out[(long)bt*10 + a] = val + advs[a] - m;
            out[16000 + bt] = ((const float*)taus_raw)[bt];
        }
    }
}

// ---------------- launch ----------------
extern "C" void kernel_launch(void* const* d_in, const int* in_sizes, int n_in,
                              void* d_out, int out_size, void* d_ws, size_t ws_size,
                              hipStream_t stream){
    (void)in_sizes; (void)n_in; (void)out_size; (void)ws_size;
    float* ws = (float*)d_ws;
    const int* ei = (const int*)d_in[1];
    const int* et = (const int*)d_in[2];

    hipMemsetAsync(ws + O_DEG, 0, (size_t)(2*NN)*4, stream);

    k_pre<<<626, 256, 0, stream>>>((const unsigned short*)d_in[3], ei, ws);
    k_scan<<<1, 256, 0, stream>>>(ws);

    ConvArgs ca;
    static const long conv_o[38] = {
        O_X, -1, -1, O_TAU, O_W1, O_Q1, O_K1, O_B1, O_W2, O_Q2, O_K2, O_B2, O_CW, O_CB,
        O_F1W, O_F1B, O_F1SW, O_F1SB, O_F1EW, O_F1EB,
        O_F2W, O_F2B, O_F2SW, O_F2SB, O_F2EW, O_F2EB,
        O_AW, O_AB, O_ASW, O_ASB, O_AEW, O_AEB,
        O_VW, O_VB, O_VSW, O_VSB, O_VEW, O_VEB };
    static const int conv_n[38] = {
        40000, 0, 0, 1600, 4096, 2048, 2048, 128, 262144, 2048, 2048, 128, 8192, 128,
        16384, 128, 16384, 128, 16384, 128,
        16384, 128, 16384, 128, 16384, 128,
        1280, 10, 1280, 10, 1280, 10,
        128, 1, 128, 1, 128, 1 };
    for (int i = 0; i < 38; i++){ ca.src[i] = d_in[i]; ca.off[i] = conv_o[i]; ca.n[i] = conv_n[i]; }
    k_conv_scatter<<<dim3(625, 39), 256, 0, stream>>>(ca, ei, ws);

    k_prep<<<dim3(1024, 4), 256, 0, stream>>>(ws);

    k_node1<<<20000, 128, 0, stream>>>(ei, et, ws);

    k_xw2_mfma<<<dim3(157, 16), 256, 0, stream>>>(ws);
    k_aqk<<<1250, 256, 0, stream>>>(ws);
    k_node2<<<20000, 128, 0, stream>>>(ei, et, ws);

    k_pool<<<200, 128, 0, stream>>>(ws);
    k_tail<<<1600, 128, 0, stream>>>(ws, d_out, d_in[3]);
}